// Round 4
// baseline (268.313 us; speedup 1.0000x reference)
//
#include <hip/hip_runtime.h>
#include <cstdint>

// Problem constants: B=4, S=1024, D=768, H=12, dh=64
#define BB 4
#define SS 1024
#define DD 768
#define HH 12
#define DH 64

typedef unsigned short u16;
typedef unsigned int   u32;
typedef __attribute__((ext_vector_type(8))) short bf16x8;
typedef __attribute__((ext_vector_type(4))) float f32x4;

// fp32 -> bf16 RNE (finite values)
__device__ __forceinline__ u16 f2bf(float f) {
    u32 u = __float_as_uint(f);
    u += 0x7fffu + ((u >> 16) & 1u);
    return (u16)(u >> 16);
}
__device__ __forceinline__ float b2f(u32 lo16) {
    return __uint_as_float(lo16 << 16);
}
__device__ __forceinline__ u32 pack2(float a, float b) {
    return (u32)f2bf(a) | ((u32)f2bf(b) << 16);
}

// async global->LDS, 16 B per lane, LDS dest must be wave-uniform base (+lane*16)
#define ASYNC16(gp, lp) __builtin_amdgcn_global_load_lds( \
    (const __attribute__((address_space(1))) void*)(gp),  \
    (__attribute__((address_space(3))) void*)(lp), 16, 0, 0)

// ---------------- MFMA GEMM body (NT: A[M,K], B[N,K], both K-contiguous bf16) ----
// Tile BM_ x BN_, BK=32, 256 threads = 4 waves in 2x2; wave region (BM_/2)x(BN_/2).
// mfma_f32_16x16x32_bf16; frag layouts per learn_hip m89/m91:
//   A: lane holds A[m=lane&15][k=(lane>>4)*8 + j]
//   B: lane holds Bt[n=lane&15][k=(lane>>4)*8 + j]  (NT rows)
//   C/D: col = lane&15, row = (lane>>4)*4 + reg
template<int BM_, int BN_, class Epi>
__device__ __forceinline__ void mfma_gemm(
    const u16* __restrict__ A, const u16* __restrict__ B,
    int K, int lda, int ldb, int m0, int n0, const Epi& epi)
{
    constexpr int MI = BM_ / 32;   // 16x16 frags per wave along m
    constexpr int NJ = BN_ / 32;
    __shared__ u16 Alds[BM_ * 32];
    __shared__ u16 Blds[BN_ * 32];

    const int tid  = threadIdx.x;
    const int wave = tid >> 6;
    const int lane = tid & 63;
    const int wr = wave >> 1, wc = wave & 1;

    const int ar = lane >> 2;          // staging: row within 16-row group
    const int ac = (lane & 3) * 8;     // staging: col (8 bf16 = 16 B)

    f32x4 acc[MI][NJ] = {};

    for (int k0 = 0; k0 < K; k0 += 32) {
        __syncthreads();               // previous compute done before overwrite
#pragma unroll
        for (int j = 0; j < BM_ / 64; ++j) {
            const int rb = wave * (BM_ / 4) + j * 16;
            ASYNC16(A + (size_t)(m0 + rb + ar) * lda + k0 + ac, &Alds[rb * 32]);
        }
#pragma unroll
        for (int j = 0; j < BN_ / 64; ++j) {
            const int rb = wave * (BN_ / 4) + j * 16;
            ASYNC16(B + (size_t)(n0 + rb + ar) * ldb + k0 + ac, &Blds[rb * 32]);
        }
        __syncthreads();               // drains vmcnt (global_load_lds) + lgkm

        bf16x8 af[MI], bfr[NJ];
#pragma unroll
        for (int mi = 0; mi < MI; ++mi)
            af[mi] = *(const bf16x8*)&Alds[(wr * (BM_ / 2) + mi * 16 + (lane & 15)) * 32 + (lane >> 4) * 8];
#pragma unroll
        for (int nj = 0; nj < NJ; ++nj)
            bfr[nj] = *(const bf16x8*)&Blds[(wc * (BN_ / 2) + nj * 16 + (lane & 15)) * 32 + (lane >> 4) * 8];
#pragma unroll
        for (int mi = 0; mi < MI; ++mi)
#pragma unroll
            for (int nj = 0; nj < NJ; ++nj)
                acc[mi][nj] = __builtin_amdgcn_mfma_f32_16x16x32_bf16(
                    af[mi], bfr[nj], acc[mi][nj], 0, 0, 0);
    }

#pragma unroll
    for (int mi = 0; mi < MI; ++mi)
#pragma unroll
        for (int nj = 0; nj < NJ; ++nj)
#pragma unroll
            for (int r = 0; r < 4; ++r)
                epi(m0 + wr * (BM_ / 2) + mi * 16 + (lane >> 4) * 4 + r,
                    n0 + wc * (BN_ / 2) + nj * 16 + (lane & 15),
                    acc[mi][nj][r]);
}

// ---------------- GEMM kernels ----------------

// qkv = x @ Wqkv^T(t) + bqkv ; scatter into qb (scaled), kb, vt (transposed)
__global__ __launch_bounds__(256) void qkv_gemm_kernel(
    const u16* __restrict__ xb, const u16* __restrict__ Wt,
    const float* __restrict__ bias,
    u16* __restrict__ qb, u16* __restrict__ kb, u16* __restrict__ vt)
{
    struct Epi {
        const float* bias; u16 *qb, *kb, *vt;
        __device__ void operator()(int m, int n, float v) const {
            const float val = v + bias[n];
            const int c = n / DD;                 // block-uniform (768 = 6*128)
            const int w = n - c * DD, h = w >> 6, d = w & 63;
            const int b = m >> 10, s = m & 1023;
            if (c == 0)
                qb[(((size_t)(b * HH + h) << 10) + s) * DH + d] = f2bf(val * 0.125f);
            else if (c == 1)
                kb[(((size_t)(b * HH + h) << 10) + s) * DH + d] = f2bf(val);
            else
                vt[((size_t)(b * HH + h) * DH + d) * SS + s] = f2bf(val);
        }
    } epi{bias, qb, kb, vt};
    mfma_gemm<128, 128>(xb, Wt, DD, DD, DD, blockIdx.y * 128, blockIdx.x * 128, epi);
}

// attn[bhL, q, k] = q . k  (per head-slice; A=qb slice, B=kb slice, K=64)
__global__ __launch_bounds__(256) void qk_gemm_kernel(
    const u16* __restrict__ qb, const u16* __restrict__ kb,
    u16* __restrict__ attn, int bh0)
{
    const int bhL = blockIdx.z;
    const int bh = bh0 + bhL;
    const u16* A = qb + (size_t)bh * SS * DH;
    const u16* B = kb + (size_t)bh * SS * DH;
    u16* C = attn + (size_t)bhL * SS * SS;
    struct Epi {
        u16* C;
        __device__ void operator()(int m, int n, float v) const {
            C[(size_t)m * SS + n] = f2bf(v);
        }
    } epi{C};
    mfma_gemm<128, 128>(A, B, DH, DH, DH, blockIdx.y * 128, blockIdx.x * 128, epi);
}

// ctx[b, q, h*64+d] = attn2[bhL,q,:] . vt[bh,d,:]   (K=1024, N=64)
__global__ __launch_bounds__(256) void pv_gemm_kernel(
    const u16* __restrict__ attn2, const u16* __restrict__ vt,
    u16* __restrict__ ctx, int bh0)
{
    const int bhL = blockIdx.z;
    const int bh = bh0 + bhL;
    const int b = bh / HH, h = bh % HH;
    const u16* A = attn2 + (size_t)bhL * SS * SS;
    const u16* B = vt + (size_t)bh * DH * SS;
    u16* C = ctx + (size_t)b * SS * DD + h * DH;
    struct Epi {
        u16* C;
        __device__ void operator()(int m, int n, float v) const {
            C[(size_t)m * DD + n] = f2bf(v);
        }
    } epi{C};
    mfma_gemm<128, 64>(A, B, SS, SS, SS, blockIdx.y * 128, 0, epi);
}

// out = ctx @ Wproj^T(t) + bproj   (fp32 output)
__global__ __launch_bounds__(256) void proj_gemm_kernel(
    const u16* __restrict__ ctx, const u16* __restrict__ Wt,
    const float* __restrict__ bias, float* __restrict__ out)
{
    struct Epi {
        float* out; const float* bias;
        __device__ void operator()(int m, int n, float v) const {
            out[(size_t)m * DD + n] = v + bias[n];
        }
    } epi{out, bias};
    mfma_gemm<128, 64>(ctx, Wt, DD, DD, DD, blockIdx.y * 128, blockIdx.x * 64, epi);
}

// ---------------- mix + softmax (bf16 in, bf16 out) ----------------
// Register-resident rewrite: thread t owns columns 4t..4t+3 for ALL 12 heads.
// mix1 -> exp (no max subtraction: |logits| <~ 2, fp32-safe, softmax is
// shift-invariant) -> rowsum butterfly + one LDS combine -> fold 1/l -> mix2.
// No 48 KB LDS buffer, 1 barrier, weights via uniform (scalar) loads.
__global__ __launch_bounds__(256) void mix_softmax_kernel(
    const u16* __restrict__ attn, u16* __restrict__ attn2,
    const float* __restrict__ Wl, const float* __restrict__ bl,
    const float* __restrict__ Ww, const float* __restrict__ bw)
{
    __shared__ float redS[4][HH];

    const int tid  = threadIdx.x;
    const int wave = tid >> 6;
    const int lane = tid & 63;
    const int bL = blockIdx.x >> 10;       // local batch within chunk
    const int qi = blockIdx.x & (SS - 1);
    const size_t base = ((size_t)bL * HH * SS + qi) * SS + tid * 4;

    // load S for 12 heads (8 B each, coalesced per head), unpack
    float vin[HH][4];
#pragma unroll
    for (int h = 0; h < HH; ++h) {
        const uint2 u = *(const uint2*)&attn[base + (size_t)h * SS * SS];
        vin[h][0] = b2f(u.x & 0xffff); vin[h][1] = b2f(u.x >> 16);
        vin[h][2] = b2f(u.y & 0xffff); vin[h][3] = b2f(u.y >> 16);
    }

    // mix1 + exp + per-thread partial row-sums
    float e[HH][4];
    float psum[HH];
#pragma unroll
    for (int g = 0; g < HH; ++g) {
        const float bg = bl[g];
        float s0 = bg, s1 = bg, s2 = bg, s3 = bg;
#pragma unroll
        for (int h = 0; h < HH; ++h) {
            const float w = Wl[h * HH + g];   // uniform -> s_load
            s0 += vin[h][0] * w; s1 += vin[h][1] * w;
            s2 += vin[h][2] * w; s3 += vin[h][3] * w;
        }
        s0 = __expf(s0); s1 = __expf(s1); s2 = __expf(s2); s3 = __expf(s3);
        e[g][0] = s0; e[g][1] = s1; e[g][2] = s2; e[g][3] = s3;
        psum[g] = (s0 + s1) + (s2 + s3);
    }

    // wave butterfly, then cross-wave combine via tiny LDS
#pragma unroll
    for (int g = 0; g < HH; ++g)
#pragma unroll
        for (int off = 32; off; off >>= 1)
            psum[g] += __shfl_xor(psum[g], off);
    if (lane == 0)
#pragma unroll
        for (int g = 0; g < HH; ++g) redS[wave][g] = psum[g];
    __syncthreads();

    // fold 1/denominator into e
#pragma unroll
    for (int h = 0; h < HH; ++h) {
        const float inv = 1.0f /
            ((redS[0][h] + redS[1][h]) + (redS[2][h] + redS[3][h]));
        e[h][0] *= inv; e[h][1] *= inv; e[h][2] *= inv; e[h][3] *= inv;
    }

    // mix2 + pack + store
#pragma unroll
    for (int g = 0; g < HH; ++g) {
        const float bg = bw[g];
        float s0 = bg, s1 = bg, s2 = bg, s3 = bg;
#pragma unroll
        for (int h = 0; h < HH; ++h) {
            const float w = Ww[h * HH + g];   // uniform -> s_load
            s0 += e[h][0] * w; s1 += e[h][1] * w;
            s2 += e[h][2] * w; s3 += e[h][3] * w;
        }
        uint2 p;
        p.x = pack2(s0, s1); p.y = pack2(s2, s3);
        *(uint2*)&attn2[base + (size_t)g * SS * SS] = p;
    }
}

// ---------------- conversion kernels ----------------

// fp32 -> bf16 elementwise (n multiple of 8)
__global__ __launch_bounds__(256) void cvt_bf16_kernel(
    const float* __restrict__ in, u16* __restrict__ out, int n8)
{
    const int i = blockIdx.x * 256 + threadIdx.x;
    if (i >= n8) return;
    const float4 a = ((const float4*)in)[i * 2];
    const float4 b = ((const float4*)in)[i * 2 + 1];
    uint4 p;
    p.x = pack2(a.x, a.y); p.y = pack2(a.z, a.w);
    p.z = pack2(b.x, b.y); p.w = pack2(b.z, b.w);
    ((uint4*)out)[i] = p;
}

// fp32 [R][C] -> bf16 [C][R] (transpose + convert), 32x32 tiles
__global__ __launch_bounds__(256) void cvt_transpose_kernel(
    const float* __restrict__ in, u16* __restrict__ out, int R, int C)
{
    __shared__ float t[32][33];
    const int c0 = blockIdx.x * 32, r0 = blockIdx.y * 32;
    const int tr = threadIdx.x >> 3;
    const int tc = (threadIdx.x & 7) * 4;
    const float4 v = *(const float4*)&in[(size_t)(r0 + tr) * C + c0 + tc];
    t[tc + 0][tr] = v.x; t[tc + 1][tr] = v.y;
    t[tc + 2][tr] = v.z; t[tc + 3][tr] = v.w;
    __syncthreads();
    uint2 p;
    p.x = pack2(t[tr][tc + 0], t[tr][tc + 1]);
    p.y = pack2(t[tr][tc + 2], t[tr][tc + 3]);
    *(uint2*)&out[(size_t)(c0 + tr) * R + r0 + tc] = p;
}

// ---------------- launch ----------------
extern "C" void kernel_launch(void* const* d_in, const int* in_sizes, int n_in,
                              void* d_out, int out_size, void* d_ws, size_t ws_size,
                              hipStream_t stream)
{
    const float* x     = (const float*)d_in[0];
    const float* Wqkv  = (const float*)d_in[1];
    const float* bqkv  = (const float*)d_in[2];
    const float* Wl    = (const float*)d_in[3];
    const float* bl    = (const float*)d_in[4];
    const float* Ww    = (const float*)d_in[5];
    const float* bw    = (const float*)d_in[6];
    const float* Wproj = (const float*)d_in[7];
    const float* bproj = (const float*)d_in[8];
    float* out = (float*)d_out;

    // workspace (bf16 elems)
    const size_t N_XB  = (size_t)BB * SS * DD;        // 3,145,728
    const size_t N_QB  = (size_t)BB * HH * SS * DH;   // 3,145,728
    const size_t N_WT  = (size_t)DD * 3 * DD;         // 1,769,472
    const size_t N_WP  = (size_t)DD * DD;             //   589,824
    const size_t N_AT1 = (size_t)HH * SS * SS;        // per-batch attn chunk elems

    u16* xb  = (u16*)d_ws;
    u16* qb  = xb  + N_XB;
    u16* kb  = qb  + N_QB;
    u16* vt  = kb  + N_QB;
    u16* ctx = vt  + N_QB;
    u16* Wqkv_t = ctx + N_XB;
    u16* Wproj_t = Wqkv_t + N_WT;
    u16* attn = Wproj_t + N_WP;   // b_per * N_AT1 elems
    // attn2 placed after attn (depends on b_per)

    const size_t fixed_bytes = (size_t)(N_XB * 2 + N_QB * 3 + N_WT + N_WP) * 2;
    int b_per = BB;
    while (b_per > 1 &&
           fixed_bytes + (size_t)b_per * N_AT1 * 2 * 2 > ws_size)
        b_per >>= 1;
    const int n_iter = BB / b_per;
    u16* attn2 = attn + (size_t)b_per * N_AT1;

    const dim3 blk(256);

    // 0) conversions
    cvt_bf16_kernel<<<dim3((N_XB / 8 + 255) / 256), blk, 0, stream>>>(x, xb, (int)(N_XB / 8));
    cvt_transpose_kernel<<<dim3(3 * DD / 32, DD / 32), blk, 0, stream>>>(Wqkv, Wqkv_t, DD, 3 * DD);
    cvt_transpose_kernel<<<dim3(DD / 32, DD / 32), blk, 0, stream>>>(Wproj, Wproj_t, DD, DD);

    // 1) QKV projection (writes qb scaled, kb, vt transposed)
    qkv_gemm_kernel<<<dim3(3 * DD / 128, BB * SS / 128), blk, 0, stream>>>(
        xb, Wqkv_t, bqkv, qb, kb, vt);

    for (int it = 0; it < n_iter; ++it) {
        const int bh0 = it * b_per * HH;
        // 2) logits
        qk_gemm_kernel<<<dim3(SS / 128, SS / 128, b_per * HH), blk, 0, stream>>>(
            qb, kb, attn, bh0);
        // 3) mix1 + softmax + mix2
        mix_softmax_kernel<<<dim3(b_per * SS), blk, 0, stream>>>(
            attn, attn2, Wl, bl, Ww, bw);
        // 4) PV
        pv_gemm_kernel<<<dim3(1, SS / 128, b_per * HH), blk, 0, stream>>>(
            attn2, vt, ctx, bh0);
    }

    // 5) output projection (fp32 out + bias)
    proj_gemm_kernel<<<dim3(DD / 64, BB * SS / 128), blk, 0, stream>>>(
        ctx, Wproj_t, bproj, out);
}

// Round 5
// 261.517 us; speedup vs baseline: 1.0260x; 1.0260x over previous
//
#include <hip/hip_runtime.h>
#include <cstdint>

// Problem constants: B=4, S=1024, D=768, H=12, dh=64
#define BB 4
#define SS 1024
#define DD 768
#define HH 12
#define DH 64

typedef unsigned short u16;
typedef unsigned int   u32;
typedef __attribute__((ext_vector_type(8))) short bf16x8;
typedef __attribute__((ext_vector_type(4))) float f32x4;

// fp32 -> bf16 RNE (finite values)
__device__ __forceinline__ u16 f2bf(float f) {
    u32 u = __float_as_uint(f);
    u += 0x7fffu + ((u >> 16) & 1u);
    return (u16)(u >> 16);
}
__device__ __forceinline__ float b2f(u32 lo16) {
    return __uint_as_float(lo16 << 16);
}
__device__ __forceinline__ u32 pack2(float a, float b) {
    return (u32)f2bf(a) | ((u32)f2bf(b) << 16);
}

// async global->LDS, 16 B per lane, LDS dest must be wave-uniform base (+lane*16)
#define ASYNC16(gp, lp) __builtin_amdgcn_global_load_lds( \
    (const __attribute__((address_space(1))) void*)(gp),  \
    (__attribute__((address_space(3))) void*)(lp), 16, 0, 0)

// ---------------- MFMA GEMM body (NT: A[M,K], B[N,K], both K-contiguous bf16) ----
// Tile BM_ x BN_, BK=32, 256 threads = 4 waves in 2x2; wave region (BM_/2)x(BN_/2).
// mfma_f32_16x16x32_bf16; frag layouts per learn_hip m89/m91:
//   A: lane holds A[m=lane&15][k=(lane>>4)*8 + j]
//   B: lane holds Bt[n=lane&15][k=(lane>>4)*8 + j]  (NT rows)
//   C/D: col = lane&15, row = (lane>>4)*4 + reg
template<int BM_, int BN_, class Epi>
__device__ __forceinline__ void mfma_gemm(
    const u16* __restrict__ A, const u16* __restrict__ B,
    int K, int lda, int ldb, int m0, int n0, const Epi& epi)
{
    constexpr int MI = BM_ / 32;   // 16x16 frags per wave along m
    constexpr int NJ = BN_ / 32;
    __shared__ u16 Alds[BM_ * 32];
    __shared__ u16 Blds[BN_ * 32];

    const int tid  = threadIdx.x;
    const int wave = tid >> 6;
    const int lane = tid & 63;
    const int wr = wave >> 1, wc = wave & 1;

    const int ar = lane >> 2;          // staging: row within 16-row group
    const int ac = (lane & 3) * 8;     // staging: col (8 bf16 = 16 B)

    f32x4 acc[MI][NJ] = {};

    for (int k0 = 0; k0 < K; k0 += 32) {
        __syncthreads();               // previous compute done before overwrite
#pragma unroll
        for (int j = 0; j < BM_ / 64; ++j) {
            const int rb = wave * (BM_ / 4) + j * 16;
            ASYNC16(A + (size_t)(m0 + rb + ar) * lda + k0 + ac, &Alds[rb * 32]);
        }
#pragma unroll
        for (int j = 0; j < BN_ / 64; ++j) {
            const int rb = wave * (BN_ / 4) + j * 16;
            ASYNC16(B + (size_t)(n0 + rb + ar) * ldb + k0 + ac, &Blds[rb * 32]);
        }
        __syncthreads();               // drains vmcnt (global_load_lds) + lgkm

        bf16x8 af[MI], bfr[NJ];
#pragma unroll
        for (int mi = 0; mi < MI; ++mi)
            af[mi] = *(const bf16x8*)&Alds[(wr * (BM_ / 2) + mi * 16 + (lane & 15)) * 32 + (lane >> 4) * 8];
#pragma unroll
        for (int nj = 0; nj < NJ; ++nj)
            bfr[nj] = *(const bf16x8*)&Blds[(wc * (BN_ / 2) + nj * 16 + (lane & 15)) * 32 + (lane >> 4) * 8];
#pragma unroll
        for (int mi = 0; mi < MI; ++mi)
#pragma unroll
            for (int nj = 0; nj < NJ; ++nj)
                acc[mi][nj] = __builtin_amdgcn_mfma_f32_16x16x32_bf16(
                    af[mi], bfr[nj], acc[mi][nj], 0, 0, 0);
    }

#pragma unroll
    for (int mi = 0; mi < MI; ++mi)
#pragma unroll
        for (int nj = 0; nj < NJ; ++nj)
#pragma unroll
            for (int r = 0; r < 4; ++r)
                epi(m0 + wr * (BM_ / 2) + mi * 16 + (lane >> 4) * 4 + r,
                    n0 + wc * (BN_ / 2) + nj * 16 + (lane & 15),
                    acc[mi][nj][r]);
}

// ---------------- GEMM kernels ----------------

// qkv = x @ Wqkv^T(t) + bqkv ; scatter into qb (scaled), kb, vt (transposed)
__global__ __launch_bounds__(256) void qkv_gemm_kernel(
    const u16* __restrict__ xb, const u16* __restrict__ Wt,
    const float* __restrict__ bias,
    u16* __restrict__ qb, u16* __restrict__ kb, u16* __restrict__ vt)
{
    struct Epi {
        const float* bias; u16 *qb, *kb, *vt;
        __device__ void operator()(int m, int n, float v) const {
            const float val = v + bias[n];
            const int c = n / DD;                 // block-uniform (768 = 6*128)
            const int w = n - c * DD, h = w >> 6, d = w & 63;
            const int b = m >> 10, s = m & 1023;
            if (c == 0)
                qb[(((size_t)(b * HH + h) << 10) + s) * DH + d] = f2bf(val * 0.125f);
            else if (c == 1)
                kb[(((size_t)(b * HH + h) << 10) + s) * DH + d] = f2bf(val);
            else
                vt[((size_t)(b * HH + h) * DH + d) * SS + s] = f2bf(val);
        }
    } epi{bias, qb, kb, vt};
    mfma_gemm<128, 128>(xb, Wt, DD, DD, DD, blockIdx.y * 128, blockIdx.x * 128, epi);
}

// attn[bhL, q, k] = q . k  (per head-slice; A=qb slice, B=kb slice, K=64)
__global__ __launch_bounds__(256) void qk_gemm_kernel(
    const u16* __restrict__ qb, const u16* __restrict__ kb,
    u16* __restrict__ attn, int bh0)
{
    const int bhL = blockIdx.z;
    const int bh = bh0 + bhL;
    const u16* A = qb + (size_t)bh * SS * DH;
    const u16* B = kb + (size_t)bh * SS * DH;
    u16* C = attn + (size_t)bhL * SS * SS;
    struct Epi {
        u16* C;
        __device__ void operator()(int m, int n, float v) const {
            C[(size_t)m * SS + n] = f2bf(v);
        }
    } epi{C};
    mfma_gemm<128, 128>(A, B, DH, DH, DH, blockIdx.y * 128, blockIdx.x * 128, epi);
}

// ctx[b, q, h*64+d] = attn2[bhL,q,:] . vt[bh,d,:]   (K=1024, N=64)
__global__ __launch_bounds__(256) void pv_gemm_kernel(
    const u16* __restrict__ attn2, const u16* __restrict__ vt,
    u16* __restrict__ ctx, int bh0)
{
    const int bhL = blockIdx.z;
    const int bh = bh0 + bhL;
    const int b = bh / HH, h = bh % HH;
    const u16* A = attn2 + (size_t)bhL * SS * SS;
    const u16* B = vt + (size_t)bh * DH * SS;
    u16* C = ctx + (size_t)b * SS * DD + h * DH;
    struct Epi {
        u16* C;
        __device__ void operator()(int m, int n, float v) const {
            C[(size_t)m * DD + n] = f2bf(v);
        }
    } epi{C};
    mfma_gemm<128, 64>(A, B, SS, SS, SS, blockIdx.y * 128, 0, epi);
}

// out = ctx @ Wproj^T(t) + bproj   (fp32 output)
__global__ __launch_bounds__(256) void proj_gemm_kernel(
    const u16* __restrict__ ctx, const u16* __restrict__ Wt,
    const float* __restrict__ bias, float* __restrict__ out)
{
    struct Epi {
        float* out; const float* bias;
        __device__ void operator()(int m, int n, float v) const {
            out[(size_t)m * DD + n] = v + bias[n];
        }
    } epi{out, bias};
    mfma_gemm<128, 64>(ctx, Wt, DD, DD, DD, blockIdx.y * 128, blockIdx.x * 64, epi);
}

// ---------------- mix + softmax (bf16 in, bf16 out) ----------------
// Register-resident, spill-free restructure (R4 spilled: g-outer mix1 kept
// vin[48]+acc[48] live -> compiler capped at 48 VGPR and scratch-spilled,
// VALUBusy 89%). Now:
//   * issue all 12 head loads up front (24 VGPR of uint2 results)
//   * mix1 h-outer: unpack one head, accumulate into acc[12][4] (48 regs)
//   * exp in place, butterfly + tiny-LDS rowsum (1 barrier)
//   * mix2 g-outer STREAMING: only e[12][4] live, store each head immediately
// Peak live ~76 regs; __launch_bounds__(256,4) gives 128-VGPR budget.
__global__ __launch_bounds__(256, 4) void mix_softmax_kernel(
    const u16* __restrict__ attn, u16* __restrict__ attn2,
    const float* __restrict__ Wl, const float* __restrict__ bl,
    const float* __restrict__ Ww, const float* __restrict__ bw)
{
    __shared__ float redS[4][HH];

    const int tid  = threadIdx.x;
    const int wave = tid >> 6;
    const int lane = tid & 63;
    const int bL = blockIdx.x >> 10;       // local batch within chunk
    const int qi = blockIdx.x & (SS - 1);
    const size_t base = ((size_t)bL * HH * SS + qi) * SS + tid * 4;

    // issue all 12 loads (8 B each, coalesced per head, 2 MB apart)
    uint2 raw[HH];
#pragma unroll
    for (int h = 0; h < HH; ++h)
        raw[h] = *(const uint2*)&attn[base + (size_t)h * SS * SS];

    // mix1, h-outer accumulator form: acc[g] = bl[g] + sum_h vin[h]*Wl[h][g]
    float acc[HH][4];
#pragma unroll
    for (int g = 0; g < HH; ++g) {
        const float bg = bl[g];
        acc[g][0] = bg; acc[g][1] = bg; acc[g][2] = bg; acc[g][3] = bg;
    }
#pragma unroll
    for (int h = 0; h < HH; ++h) {
        const float v0 = b2f(raw[h].x & 0xffff), v1 = b2f(raw[h].x >> 16);
        const float v2 = b2f(raw[h].y & 0xffff), v3 = b2f(raw[h].y >> 16);
#pragma unroll
        for (int g = 0; g < HH; ++g) {
            const float w = Wl[h * HH + g];   // uniform -> s_load
            acc[g][0] += v0 * w; acc[g][1] += v1 * w;
            acc[g][2] += v2 * w; acc[g][3] += v3 * w;
        }
    }

    // exp in place (no max subtraction: mixed logits are O(2), fp32-safe;
    // softmax is shift-invariant) + per-thread partial row sums
    float psum[HH];
#pragma unroll
    for (int g = 0; g < HH; ++g) {
        acc[g][0] = __expf(acc[g][0]); acc[g][1] = __expf(acc[g][1]);
        acc[g][2] = __expf(acc[g][2]); acc[g][3] = __expf(acc[g][3]);
        psum[g] = (acc[g][0] + acc[g][1]) + (acc[g][2] + acc[g][3]);
    }

    // wave butterfly, then cross-wave combine via tiny LDS
#pragma unroll
    for (int g = 0; g < HH; ++g)
#pragma unroll
        for (int off = 32; off; off >>= 1)
            psum[g] += __shfl_xor(psum[g], off);
    if (lane == 0)
#pragma unroll
        for (int g = 0; g < HH; ++g) redS[wave][g] = psum[g];
    __syncthreads();

    // fold 1/denominator into acc (now acc == normalized P)
#pragma unroll
    for (int h = 0; h < HH; ++h) {
        const float inv = 1.0f /
            ((redS[0][h] + redS[1][h]) + (redS[2][h] + redS[3][h]));
        acc[h][0] *= inv; acc[h][1] *= inv; acc[h][2] *= inv; acc[h][3] *= inv;
    }

    // mix2, g-outer streaming: only acc stays live; store each head at once
#pragma unroll
    for (int g = 0; g < HH; ++g) {
        const float bg = bw[g];
        float s0 = bg, s1 = bg, s2 = bg, s3 = bg;
#pragma unroll
        for (int h = 0; h < HH; ++h) {
            const float w = Ww[h * HH + g];   // uniform -> s_load
            s0 += acc[h][0] * w; s1 += acc[h][1] * w;
            s2 += acc[h][2] * w; s3 += acc[h][3] * w;
        }
        uint2 p;
        p.x = pack2(s0, s1); p.y = pack2(s2, s3);
        *(uint2*)&attn2[base + (size_t)g * SS * SS] = p;
    }
}

// ---------------- conversion kernels ----------------

// fp32 -> bf16 elementwise (n multiple of 8)
__global__ __launch_bounds__(256) void cvt_bf16_kernel(
    const float* __restrict__ in, u16* __restrict__ out, int n8)
{
    const int i = blockIdx.x * 256 + threadIdx.x;
    if (i >= n8) return;
    const float4 a = ((const float4*)in)[i * 2];
    const float4 b = ((const float4*)in)[i * 2 + 1];
    uint4 p;
    p.x = pack2(a.x, a.y); p.y = pack2(a.z, a.w);
    p.z = pack2(b.x, b.y); p.w = pack2(b.z, b.w);
    ((uint4*)out)[i] = p;
}

// fp32 [R][C] -> bf16 [C][R] (transpose + convert), 32x32 tiles
__global__ __launch_bounds__(256) void cvt_transpose_kernel(
    const float* __restrict__ in, u16* __restrict__ out, int R, int C)
{
    __shared__ float t[32][33];
    const int c0 = blockIdx.x * 32, r0 = blockIdx.y * 32;
    const int tr = threadIdx.x >> 3;
    const int tc = (threadIdx.x & 7) * 4;
    const float4 v = *(const float4*)&in[(size_t)(r0 + tr) * C + c0 + tc];
    t[tc + 0][tr] = v.x; t[tc + 1][tr] = v.y;
    t[tc + 2][tr] = v.z; t[tc + 3][tr] = v.w;
    __syncthreads();
    uint2 p;
    p.x = pack2(t[tr][tc + 0], t[tr][tc + 1]);
    p.y = pack2(t[tr][tc + 2], t[tr][tc + 3]);
    *(uint2*)&out[(size_t)(c0 + tr) * R + r0 + tc] = p;
}

// ---------------- launch ----------------
extern "C" void kernel_launch(void* const* d_in, const int* in_sizes, int n_in,
                              void* d_out, int out_size, void* d_ws, size_t ws_size,
                              hipStream_t stream)
{
    const float* x     = (const float*)d_in[0];
    const float* Wqkv  = (const float*)d_in[1];
    const float* bqkv  = (const float*)d_in[2];
    const float* Wl    = (const float*)d_in[3];
    const float* bl    = (const float*)d_in[4];
    const float* Ww    = (const float*)d_in[5];
    const float* bw    = (const float*)d_in[6];
    const float* Wproj = (const float*)d_in[7];
    const float* bproj = (const float*)d_in[8];
    float* out = (float*)d_out;

    // workspace (bf16 elems)
    const size_t N_XB  = (size_t)BB * SS * DD;        // 3,145,728
    const size_t N_QB  = (size_t)BB * HH * SS * DH;   // 3,145,728
    const size_t N_WT  = (size_t)DD * 3 * DD;         // 1,769,472
    const size_t N_WP  = (size_t)DD * DD;             //   589,824
    const size_t N_AT1 = (size_t)HH * SS * SS;        // per-batch attn chunk elems

    u16* xb  = (u16*)d_ws;
    u16* qb  = xb  + N_XB;
    u16* kb  = qb  + N_QB;
    u16* vt  = kb  + N_QB;
    u16* ctx = vt  + N_QB;
    u16* Wqkv_t = ctx + N_XB;
    u16* Wproj_t = Wqkv_t + N_WT;
    u16* attn = Wproj_t + N_WP;   // b_per * N_AT1 elems
    // attn2 placed after attn (depends on b_per)

    const size_t fixed_bytes = (size_t)(N_XB * 2 + N_QB * 3 + N_WT + N_WP) * 2;
    int b_per = BB;
    while (b_per > 1 &&
           fixed_bytes + (size_t)b_per * N_AT1 * 2 * 2 > ws_size)
        b_per >>= 1;
    const int n_iter = BB / b_per;
    u16* attn2 = attn + (size_t)b_per * N_AT1;

    const dim3 blk(256);

    // 0) conversions
    cvt_bf16_kernel<<<dim3((N_XB / 8 + 255) / 256), blk, 0, stream>>>(x, xb, (int)(N_XB / 8));
    cvt_transpose_kernel<<<dim3(3 * DD / 32, DD / 32), blk, 0, stream>>>(Wqkv, Wqkv_t, DD, 3 * DD);
    cvt_transpose_kernel<<<dim3(DD / 32, DD / 32), blk, 0, stream>>>(Wproj, Wproj_t, DD, DD);

    // 1) QKV projection (writes qb scaled, kb, vt transposed)
    qkv_gemm_kernel<<<dim3(3 * DD / 128, BB * SS / 128), blk, 0, stream>>>(
        xb, Wqkv_t, bqkv, qb, kb, vt);

    for (int it = 0; it < n_iter; ++it) {
        const int bh0 = it * b_per * HH;
        // 2) logits
        qk_gemm_kernel<<<dim3(SS / 128, SS / 128, b_per * HH), blk, 0, stream>>>(
            qb, kb, attn, bh0);
        // 3) mix1 + softmax + mix2
        mix_softmax_kernel<<<dim3(b_per * SS), blk, 0, stream>>>(
            attn, attn2, Wl, bl, Ww, bw);
        // 4) PV
        pv_gemm_kernel<<<dim3(1, SS / 128, b_per * HH), blk, 0, stream>>>(
            attn2, vt, ctx, bh0);
    }

    // 5) output projection (fp32 out + bias)
    proj_gemm_kernel<<<dim3(DD / 64, BB * SS / 128), blk, 0, stream>>>(
        ctx, Wproj_t, bproj, out);
}